// Round 25
// baseline (333.890 us; speedup 1.0000x reference)
//
#include <hip/hip_runtime.h>
#include <math.h>

// Pipeline (d_out doubles as scratch: Ah fp16 67MB + Wf fp16 1.5MB):
//   k0 cvt_fp16(A):  A fp32 -> Ah fp16 row-major in d_out
//   k0b cvt_w_frag:  w_qkv fp32 -> Wf fp16 in FRAGMENT order
//   k1 gemm:         qkv16 = fp16(Ah @ W^T + bias) in d_ws.
//                    r25: NO-LDS main loop. Both A and W fragments stream
//                    directly global->registers (L2/L3-resident; W proven
//                    since r15). Zero barriers, zero LDS staging; depth-2
//                    named register sets; fully unrolled K loop.
//                    Rationale: r22's loop was LDS-BW-bound (96KB/step/CU
//                    ~750cyc vs ~310cyc MFMA).
//   k2 scramble:     qkv16 -> out fp32 (r18-verified)

typedef _Float16 half8 __attribute__((ext_vector_type(8)));
typedef _Float16 half4 __attribute__((ext_vector_type(4)));
typedef __fp16 fp16x2 __attribute__((ext_vector_type(2)));
typedef float f32x4 __attribute__((ext_vector_type(4)));

__device__ __forceinline__ half8 pk8(const float4 x, const float4 y) {
    fp16x2 a = __builtin_amdgcn_cvt_pkrtz(x.x, x.y);
    fp16x2 b = __builtin_amdgcn_cvt_pkrtz(x.z, x.w);
    fp16x2 c = __builtin_amdgcn_cvt_pkrtz(y.x, y.y);
    fp16x2 d = __builtin_amdgcn_cvt_pkrtz(y.z, y.w);
    half8 r;
    r[0] = (_Float16)a[0]; r[1] = (_Float16)a[1];
    r[2] = (_Float16)b[0]; r[3] = (_Float16)b[1];
    r[4] = (_Float16)c[0]; r[5] = (_Float16)c[1];
    r[6] = (_Float16)d[0]; r[7] = (_Float16)d[1];
    return r;
}

// ---------------------------------------------------------------------------
// k0: streaming fp32 -> fp16
// ---------------------------------------------------------------------------
__global__ __launch_bounds__(256) void cvt_fp16(
    const float* __restrict__ src, _Float16* __restrict__ dst)
{
    const size_t i = (size_t)blockIdx.x * 256 + threadIdx.x;
    const float4 x = *reinterpret_cast<const float4*>(src + i * 8);
    const float4 y = *reinterpret_cast<const float4*>(src + i * 8 + 4);
    *reinterpret_cast<half8*>(dst + i * 8) = pk8(x, y);
}

// ---------------------------------------------------------------------------
// k0b: W fp32 [1536,512] -> Wf fp16 fragment-ordered (98304 threads)
// ---------------------------------------------------------------------------
__global__ __launch_bounds__(256) void cvt_w_frag(
    const float* __restrict__ W, _Float16* __restrict__ Wf)
{
    const int gid  = blockIdx.x * 256 + threadIdx.x;   // 0..98303
    const int lane = gid & 63;
    const int nf   = (gid >> 6) & 3;
    const int ks   = (gid >> 8) & 15;
    const int ntw  = gid >> 12;                        // 0..23
    const float* src =
        W + (size_t)(ntw * 64 + nf * 16 + (lane & 15)) * 512 +
        ks * 32 + (lane >> 4) * 8;
    const float4 x = *reinterpret_cast<const float4*>(src);
    const float4 y = *reinterpret_cast<const float4*>(src + 4);
    *reinterpret_cast<half8*>(Wf + (size_t)gid * 8) = pk8(x, y);
}

// ---------------------------------------------------------------------------
// k1: C16[65536,1536] = fp16(Ah @ W^T + bias).  BM=BN=128, BK=32, 4 waves
// (2x2, 64x64 each). NO LDS in the main loop; LDS only for the epilogue
// transpose. A-frag: rows wm*64+mf*16+l15, 16B at k-offset t*32+kq*8.
// W-frag: fragment-ordered Wf (nt*2+wn group).
// ---------------------------------------------------------------------------
__global__ __launch_bounds__(256, 3) void gemm_nolds(
    const _Float16* __restrict__ Ah, const _Float16* __restrict__ Wf,
    const float* __restrict__ bias, _Float16* __restrict__ C)
{
    __shared__ __align__(16) float eplds[4352];     // 17.4 KB, epilogue only

    const int lin = blockIdx.x;                     // 6144 blocks, %8==0
    const int swz = (lin & 7) * 768 + (lin >> 3);
    const int nt = swz % 12, mt = swz / 12;         // nt fastest: A L2-reuse
    const int row0 = mt * 128, col0 = nt * 128;

    const int tid = threadIdx.x, wid = tid >> 6, lane = tid & 63;
    const int wm = wid >> 1, wn = wid & 1, l15 = lane & 15, kq = lane >> 4;

    // per-fragment global base pointers
    const _Float16* pA0 = Ah + (size_t)(row0 + wm * 64 +  0 + l15) * 512 + kq * 8;
    const _Float16* pA1 = Ah + (size_t)(row0 + wm * 64 + 16 + l15) * 512 + kq * 8;
    const _Float16* pA2 = Ah + (size_t)(row0 + wm * 64 + 32 + l15) * 512 + kq * 8;
    const _Float16* pA3 = Ah + (size_t)(row0 + wm * 64 + 48 + l15) * 512 + kq * 8;
    const _Float16* pW  = Wf + (size_t)(nt * 2 + wn) * 32768 + lane * 8;

    f32x4 acc[4][4];
#pragma unroll
    for (int i = 0; i < 4; ++i)
#pragma unroll
        for (int j = 0; j < 4; ++j) acc[i][j] = (f32x4)0.f;

    half8 aA[4], aB[4], wA[4], wB[4];   // two named A/W register sets

#define LOADA(DST, T)                                                          \
    do {                                                                       \
        DST[0] = *reinterpret_cast<const half8*>(pA0 + (T) * 32);              \
        DST[1] = *reinterpret_cast<const half8*>(pA1 + (T) * 32);              \
        DST[2] = *reinterpret_cast<const half8*>(pA2 + (T) * 32);              \
        DST[3] = *reinterpret_cast<const half8*>(pA3 + (T) * 32);              \
    } while (0)

#define LOADW(DST, T)                                                          \
    do {                                                                       \
        DST[0] = *reinterpret_cast<const half8*>(pW + (T) * 2048 +    0);      \
        DST[1] = *reinterpret_cast<const half8*>(pW + (T) * 2048 +  512);      \
        DST[2] = *reinterpret_cast<const half8*>(pW + (T) * 2048 + 1024);      \
        DST[3] = *reinterpret_cast<const half8*>(pW + (T) * 2048 + 1536);      \
    } while (0)

#define FRAG(AS, WS)                                                           \
    do {                                                                       \
        __builtin_amdgcn_s_setprio(1);                                         \
        _Pragma("unroll")                                                      \
        for (int nf = 0; nf < 4; ++nf)                                         \
            _Pragma("unroll")                                                  \
            for (int mf = 0; mf < 4; ++mf)                                     \
                acc[mf][nf] = __builtin_amdgcn_mfma_f32_16x16x32_f16(          \
                    AS[mf], WS[nf], acc[mf][nf], 0, 0, 0);                     \
        __builtin_amdgcn_s_setprio(0);                                         \
    } while (0)

    // prologue: sets A<-tile0, B<-tile1
    LOADA(aA, 0); LOADW(wA, 0);
    LOADA(aB, 1); LOADW(wB, 1);

#pragma unroll
    for (int t = 0; t < 16; t += 2) {
        FRAG(aA, wA);
        if (t + 2 < 16) { LOADA(aA, t + 2); LOADW(wA, t + 2); }
        FRAG(aB, wB);
        if (t + 3 < 16) { LOADA(aB, t + 3); LOADW(wB, t + 3); }
    }
#undef FRAG
#undef LOADW
#undef LOADA

    // ---- epilogue: per-wave LDS transpose -> fp16 half4 stores.
    // __syncthreads() fences between scatter and gather (r17-verified).
    float* wbase = eplds + wid * 1088;
    const float4 bv4 = *reinterpret_cast<const float4*>(
        &bias[col0 + wn * 64 + l15 * 4]);

#pragma unroll
    for (int mf = 0; mf < 4; ++mf) {
#pragma unroll
        for (int nf = 0; nf < 4; ++nf)
#pragma unroll
            for (int j = 0; j < 4; ++j)
                wbase[(kq * 4 + j) * 68 + nf * 16 + l15] = acc[mf][nf][j];
        __syncthreads();   // writes visible before cross-lane reads
#pragma unroll
        for (int i = 0; i < 4; ++i) {
            const int r16 = i * 4 + kq;
            float4 v = *reinterpret_cast<float4*>(wbase + r16 * 68 + l15 * 4);
            half4 h;
            h[0] = (_Float16)(v.x + bv4.x);   // RNE
            h[1] = (_Float16)(v.y + bv4.y);
            h[2] = (_Float16)(v.z + bv4.z);
            h[3] = (_Float16)(v.w + bv4.w);
            const int r = row0 + wm * 64 + mf * 16 + r16;
            *reinterpret_cast<half4*>(
                &C[(size_t)r * 1536 + col0 + wn * 64 + l15 * 4]) = h;
        }
        __syncthreads();   // reads done before next mf's scatter overwrites
    }
}

// ---------------------------------------------------------------------------
// k2: scrambled elementwise softmax; qkv FP16 (r18-verified)
// ---------------------------------------------------------------------------
__global__ __launch_bounds__(256) void attn_scramble(
    const _Float16* __restrict__ qkv, float* __restrict__ out)
{
    __shared__ float Ks[64][68];    // [hwlo][d'], rows 272B (16B-aligned)
    const int bid = blockIdx.x;
    const int hw6 = bid & 63;
    const int n   = (bid >> 6) & 7;
    const int b   = bid >> 9;
    const int kn  = (n + 7) & 7;
    const int t   = threadIdx.x;
    {
        const int lx = t & 7;       // 8 lanes x half8 cover one d'-row (64)
        const int rp = t >> 3;      // 32 d'-rows per pass
#pragma unroll
        for (int p = 0; p < 2; ++p) {
            const int dp = p * 32 + rp;
            const half8 kv = *reinterpret_cast<const half8*>(
                &qkv[(size_t)(b * 4096 + dp * 64 + hw6) * 1536 + 512 +
                     kn * 64 + lx * 8]);
#pragma unroll
            for (int e = 0; e < 8; ++e)
                Ks[lx * 8 + e][dp] = (float)kv[e];
        }
    }
    __syncthreads();
    const int row = t >> 2;
    const int tl  = t & 3;
    const size_t rbase = (size_t)(b * 4096 + hw6 * 64 + row) * 1536;
    float s[16];
    {
        const _Float16* qp = qkv + rbase + n * 64 + tl * 16;
        const half8 q0 = *reinterpret_cast<const half8*>(qp);
        const half8 q1 = *reinterpret_cast<const half8*>(qp + 8);
        float q[16], kk[16];
#pragma unroll
        for (int e = 0; e < 8; ++e) {
            q[e] = (float)q0[e];
            q[8 + e] = (float)q1[e];
        }
#pragma unroll
        for (int u = 0; u < 4; ++u)
            *reinterpret_cast<float4*>(&kk[u * 4]) =
                *reinterpret_cast<const float4*>(&Ks[row][tl * 16 + u * 4]);
        float m = -1e30f;
#pragma unroll
        for (int u = 0; u < 16; ++u) {
            s[u] = 0.125f * q[u] * kk[u];
            m = fmaxf(m, s[u]);
        }
        m = fmaxf(m, __shfl_xor(m, 1));
        m = fmaxf(m, __shfl_xor(m, 2));
        float sum = 0.f;
#pragma unroll
        for (int u = 0; u < 16; ++u) {
            s[u] = __expf(s[u] - m);
            sum += s[u];
        }
        sum += __shfl_xor(sum, 1);
        sum += __shfl_xor(sum, 2);
        const float inv = 1.0f / sum;
#pragma unroll
        for (int u = 0; u < 16; ++u) s[u] *= inv;
    }
    const _Float16* vp = qkv + rbase + 1024 + kn * 64 + tl * 16;
    const half8 v0 = *reinterpret_cast<const half8*>(vp);
    const half8 v1 = *reinterpret_cast<const half8*>(vp + 8);
    const int vb = b >> 3, fr = b & 7;
    float* op = out +
        ((size_t)(((vb * 8 + (hw6 >> 3)) * 64 + ((hw6 & 7) * 8 + (row >> 3))) * 64 +
                  ((row & 7) * 8 + n)) * 512) + fr * 64 + tl * 16;
    float4 o0, o1, o2, o3;
    o0.x = s[0]  * (float)v0[0]; o0.y = s[1]  * (float)v0[1];
    o0.z = s[2]  * (float)v0[2]; o0.w = s[3]  * (float)v0[3];
    o1.x = s[4]  * (float)v0[4]; o1.y = s[5]  * (float)v0[5];
    o1.z = s[6]  * (float)v0[6]; o1.w = s[7]  * (float)v0[7];
    o2.x = s[8]  * (float)v1[0]; o2.y = s[9]  * (float)v1[1];
    o2.z = s[10] * (float)v1[2]; o2.w = s[11] * (float)v1[3];
    o3.x = s[12] * (float)v1[4]; o3.y = s[13] * (float)v1[5];
    o3.z = s[14] * (float)v1[6]; o3.w = s[15] * (float)v1[7];
    *reinterpret_cast<float4*>(op)      = o0;
    *reinterpret_cast<float4*>(op + 4)  = o1;
    *reinterpret_cast<float4*>(op + 8)  = o2;
    *reinterpret_cast<float4*>(op + 12) = o3;
}

// ---------------------------------------------------------------------------
extern "C" void kernel_launch(void* const* d_in, const int* in_sizes, int n_in,
                              void* d_out, int out_size, void* d_ws, size_t ws_size,
                              hipStream_t stream) {
    const float* hs = (const float*)d_in[0];  // [65536,512]
    const float* w  = (const float*)d_in[1];  // [1536,512]
    const float* bq = (const float*)d_in[2];  // [1536]
    float* out = (float*)d_out;
    _Float16* qkv = (_Float16*)d_ws;          // 201,326,592 B (fits)

    // d_out as scratch: Ah (67,108,864 B) | Wf (1,572,864 B)
    _Float16* Asp = (_Float16*)d_out;
    _Float16* Wf  = Asp + 33554432;           // 65536*512

    cvt_fp16<<<16384, 256, 0, stream>>>(hs, Asp);
    cvt_w_frag<<<384, 256, 0, stream>>>(w, Wf);
    gemm_nolds<<<6144, 256, 0, stream>>>(Asp, Wf, bq, qkv);
    attn_scramble<<<8192, 256, 0, stream>>>(qkv, out);
}

// Round 26
// 234.005 us; speedup vs baseline: 1.4268x; 1.4268x over previous
//
#include <hip/hip_runtime.h>
#include <math.h>

// Pipeline (d_out doubles as scratch: Af fp16 67MB + Wf fp16 1.5MB):
//   k0 cvt_a_frag:  A fp32 -> Af fp16 in MFMA FRAGMENT order
//   k0b cvt_w_frag: w_qkv fp32 -> Wf fp16 in FRAGMENT order
//   k1 gemm:        qkv16 = fp16(Af @ W^T + bias) in d_ws.
//                   r26: NO-LDS main loop with BOTH operands fragment-
//                   ordered -> every load is 16B/lane fully coalesced
//                   (r25's failure was A's 16-way scattered segments).
//                   Zero barriers; depth-2 named register sets.
//   k2 scramble:    qkv16 -> out fp32 (r18-verified)

typedef _Float16 half8 __attribute__((ext_vector_type(8)));
typedef _Float16 half4 __attribute__((ext_vector_type(4)));
typedef __fp16 fp16x2 __attribute__((ext_vector_type(2)));
typedef float f32x4 __attribute__((ext_vector_type(4)));

__device__ __forceinline__ half8 pk8(const float4 x, const float4 y) {
    fp16x2 a = __builtin_amdgcn_cvt_pkrtz(x.x, x.y);
    fp16x2 b = __builtin_amdgcn_cvt_pkrtz(x.z, x.w);
    fp16x2 c = __builtin_amdgcn_cvt_pkrtz(y.x, y.y);
    fp16x2 d = __builtin_amdgcn_cvt_pkrtz(y.z, y.w);
    half8 r;
    r[0] = (_Float16)a[0]; r[1] = (_Float16)a[1];
    r[2] = (_Float16)b[0]; r[3] = (_Float16)b[1];
    r[4] = (_Float16)c[0]; r[5] = (_Float16)c[1];
    r[6] = (_Float16)d[0]; r[7] = (_Float16)d[1];
    return r;
}

// ---------------------------------------------------------------------------
// k0: A fp32 [65536,512] -> Af fp16 fragment-ordered.
// Af[((gm*16+ks)*64+lane)*8+e] = A[gm*16+(lane&15)][ks*32+(lane>>4)*8+e]
// gid = (gm*16+ks)*64+lane;  4,194,304 threads, 8 floats each.
// ---------------------------------------------------------------------------
__global__ __launch_bounds__(256) void cvt_a_frag(
    const float* __restrict__ A, _Float16* __restrict__ Af)
{
    const int gid  = blockIdx.x * 256 + threadIdx.x;
    const int lane = gid & 63;
    const int ks   = (gid >> 6) & 15;
    const int gm   = gid >> 10;
    const float* src =
        A + (size_t)(gm * 16 + (lane & 15)) * 512 + ks * 32 + (lane >> 4) * 8;
    const float4 x = *reinterpret_cast<const float4*>(src);
    const float4 y = *reinterpret_cast<const float4*>(src + 4);
    *reinterpret_cast<half8*>(Af + (size_t)gid * 8) = pk8(x, y);
}

// ---------------------------------------------------------------------------
// k0b: W fp32 [1536,512] -> Wf fp16 fragment-ordered (98304 threads)
// ---------------------------------------------------------------------------
__global__ __launch_bounds__(256) void cvt_w_frag(
    const float* __restrict__ W, _Float16* __restrict__ Wf)
{
    const int gid  = blockIdx.x * 256 + threadIdx.x;   // 0..98303
    const int lane = gid & 63;
    const int nf   = (gid >> 6) & 3;
    const int ks   = (gid >> 8) & 15;
    const int ntw  = gid >> 12;                        // 0..23
    const float* src =
        W + (size_t)(ntw * 64 + nf * 16 + (lane & 15)) * 512 +
        ks * 32 + (lane >> 4) * 8;
    const float4 x = *reinterpret_cast<const float4*>(src);
    const float4 y = *reinterpret_cast<const float4*>(src + 4);
    *reinterpret_cast<half8*>(Wf + (size_t)gid * 8) = pk8(x, y);
}

// ---------------------------------------------------------------------------
// k1: C16[65536,1536] = fp16(Af @ W^T + bias).  BM=BN=128, BK=32, 4 waves
// (2x2, 64x64 each). NO LDS in the main loop (epilogue transpose only).
// A-frag mf at K-tile T: Af + (gm0+mf)*8192 + T*512 + lane*8, gm0=row0/16+wm*4.
// W-frag nf at K-tile T: Wf + (nt*2+wn)*32768 + T*2048 + nf*512 + lane*8.
// Both are 16B/lane contiguous (1KB/wave) loads.
// ---------------------------------------------------------------------------
__global__ __launch_bounds__(256, 3) void gemm_nolds(
    const _Float16* __restrict__ Af, const _Float16* __restrict__ Wf,
    const float* __restrict__ bias, _Float16* __restrict__ C)
{
    __shared__ __align__(16) float eplds[4352];     // 17.4 KB, epilogue only

    const int lin = blockIdx.x;                     // 6144 blocks, %8==0
    const int swz = (lin & 7) * 768 + (lin >> 3);
    const int nt = swz % 12, mt = swz / 12;         // nt fastest: A L2-reuse
    const int row0 = mt * 128, col0 = nt * 128;

    const int tid = threadIdx.x, wid = tid >> 6, lane = tid & 63;
    const int wm = wid >> 1, wn = wid & 1, l15 = lane & 15, kq = lane >> 4;

    const _Float16* pAf = Af + (size_t)(row0 / 16 + wm * 4) * 8192 + lane * 8;
    const _Float16* pW  = Wf + (size_t)(nt * 2 + wn) * 32768 + lane * 8;

    f32x4 acc[4][4];
#pragma unroll
    for (int i = 0; i < 4; ++i)
#pragma unroll
        for (int j = 0; j < 4; ++j) acc[i][j] = (f32x4)0.f;

    half8 aA[4], aB[4], wA[4], wB[4];   // two named A/W register sets

#define LOADA(DST, T)                                                          \
    do {                                                                       \
        DST[0] = *reinterpret_cast<const half8*>(pAf +     0 + (T) * 512);     \
        DST[1] = *reinterpret_cast<const half8*>(pAf +  8192 + (T) * 512);     \
        DST[2] = *reinterpret_cast<const half8*>(pAf + 16384 + (T) * 512);     \
        DST[3] = *reinterpret_cast<const half8*>(pAf + 24576 + (T) * 512);     \
    } while (0)

#define LOADW(DST, T)                                                          \
    do {                                                                       \
        DST[0] = *reinterpret_cast<const half8*>(pW + (T) * 2048 +    0);      \
        DST[1] = *reinterpret_cast<const half8*>(pW + (T) * 2048 +  512);      \
        DST[2] = *reinterpret_cast<const half8*>(pW + (T) * 2048 + 1024);      \
        DST[3] = *reinterpret_cast<const half8*>(pW + (T) * 2048 + 1536);      \
    } while (0)

#define FRAG(AS, WS)                                                           \
    do {                                                                       \
        __builtin_amdgcn_s_setprio(1);                                         \
        _Pragma("unroll")                                                      \
        for (int nf = 0; nf < 4; ++nf)                                         \
            _Pragma("unroll")                                                  \
            for (int mf = 0; mf < 4; ++mf)                                     \
                acc[mf][nf] = __builtin_amdgcn_mfma_f32_16x16x32_f16(          \
                    AS[mf], WS[nf], acc[mf][nf], 0, 0, 0);                     \
        __builtin_amdgcn_s_setprio(0);                                         \
    } while (0)

    // prologue: sets A<-tile0, B<-tile1
    LOADA(aA, 0); LOADW(wA, 0);
    LOADA(aB, 1); LOADW(wB, 1);

#pragma unroll
    for (int t = 0; t < 16; t += 2) {
        FRAG(aA, wA);
        if (t + 2 < 16) { LOADA(aA, t + 2); LOADW(wA, t + 2); }
        FRAG(aB, wB);
        if (t + 3 < 16) { LOADA(aB, t + 3); LOADW(wB, t + 3); }
    }
#undef FRAG
#undef LOADW
#undef LOADA

    // ---- epilogue: per-wave LDS transpose -> fp16 half4 stores.
    // __syncthreads() fences between scatter and gather (r17-verified).
    float* wbase = eplds + wid * 1088;
    const float4 bv4 = *reinterpret_cast<const float4*>(
        &bias[col0 + wn * 64 + l15 * 4]);

#pragma unroll
    for (int mf = 0; mf < 4; ++mf) {
#pragma unroll
        for (int nf = 0; nf < 4; ++nf)
#pragma unroll
            for (int j = 0; j < 4; ++j)
                wbase[(kq * 4 + j) * 68 + nf * 16 + l15] = acc[mf][nf][j];
        __syncthreads();   // writes visible before cross-lane reads
#pragma unroll
        for (int i = 0; i < 4; ++i) {
            const int r16 = i * 4 + kq;
            float4 v = *reinterpret_cast<float4*>(wbase + r16 * 68 + l15 * 4);
            half4 h;
            h[0] = (_Float16)(v.x + bv4.x);   // RNE
            h[1] = (_Float16)(v.y + bv4.y);
            h[2] = (_Float16)(v.z + bv4.z);
            h[3] = (_Float16)(v.w + bv4.w);
            const int r = row0 + wm * 64 + mf * 16 + r16;
            *reinterpret_cast<half4*>(
                &C[(size_t)r * 1536 + col0 + wn * 64 + l15 * 4]) = h;
        }
        __syncthreads();   // reads done before next mf's scatter overwrites
    }
}

// ---------------------------------------------------------------------------
// k2: scrambled elementwise softmax; qkv FP16 (r18-verified)
// ---------------------------------------------------------------------------
__global__ __launch_bounds__(256) void attn_scramble(
    const _Float16* __restrict__ qkv, float* __restrict__ out)
{
    __shared__ float Ks[64][68];    // [hwlo][d'], rows 272B (16B-aligned)
    const int bid = blockIdx.x;
    const int hw6 = bid & 63;
    const int n   = (bid >> 6) & 7;
    const int b   = bid >> 9;
    const int kn  = (n + 7) & 7;
    const int t   = threadIdx.x;
    {
        const int lx = t & 7;       // 8 lanes x half8 cover one d'-row (64)
        const int rp = t >> 3;      // 32 d'-rows per pass
#pragma unroll
        for (int p = 0; p < 2; ++p) {
            const int dp = p * 32 + rp;
            const half8 kv = *reinterpret_cast<const half8*>(
                &qkv[(size_t)(b * 4096 + dp * 64 + hw6) * 1536 + 512 +
                     kn * 64 + lx * 8]);
#pragma unroll
            for (int e = 0; e < 8; ++e)
                Ks[lx * 8 + e][dp] = (float)kv[e];
        }
    }
    __syncthreads();
    const int row = t >> 2;
    const int tl  = t & 3;
    const size_t rbase = (size_t)(b * 4096 + hw6 * 64 + row) * 1536;
    float s[16];
    {
        const _Float16* qp = qkv + rbase + n * 64 + tl * 16;
        const half8 q0 = *reinterpret_cast<const half8*>(qp);
        const half8 q1 = *reinterpret_cast<const half8*>(qp + 8);
        float q[16], kk[16];
#pragma unroll
        for (int e = 0; e < 8; ++e) {
            q[e] = (float)q0[e];
            q[8 + e] = (float)q1[e];
        }
#pragma unroll
        for (int u = 0; u < 4; ++u)
            *reinterpret_cast<float4*>(&kk[u * 4]) =
                *reinterpret_cast<const float4*>(&Ks[row][tl * 16 + u * 4]);
        float m = -1e30f;
#pragma unroll
        for (int u = 0; u < 16; ++u) {
            s[u] = 0.125f * q[u] * kk[u];
            m = fmaxf(m, s[u]);
        }
        m = fmaxf(m, __shfl_xor(m, 1));
        m = fmaxf(m, __shfl_xor(m, 2));
        float sum = 0.f;
#pragma unroll
        for (int u = 0; u < 16; ++u) {
            s[u] = __expf(s[u] - m);
            sum += s[u];
        }
        sum += __shfl_xor(sum, 1);
        sum += __shfl_xor(sum, 2);
        const float inv = 1.0f / sum;
#pragma unroll
        for (int u = 0; u < 16; ++u) s[u] *= inv;
    }
    const _Float16* vp = qkv + rbase + 1024 + kn * 64 + tl * 16;
    const half8 v0 = *reinterpret_cast<const half8*>(vp);
    const half8 v1 = *reinterpret_cast<const half8*>(vp + 8);
    const int vb = b >> 3, fr = b & 7;
    float* op = out +
        ((size_t)(((vb * 8 + (hw6 >> 3)) * 64 + ((hw6 & 7) * 8 + (row >> 3))) * 64 +
                  ((row & 7) * 8 + n)) * 512) + fr * 64 + tl * 16;
    float4 o0, o1, o2, o3;
    o0.x = s[0]  * (float)v0[0]; o0.y = s[1]  * (float)v0[1];
    o0.z = s[2]  * (float)v0[2]; o0.w = s[3]  * (float)v0[3];
    o1.x = s[4]  * (float)v0[4]; o1.y = s[5]  * (float)v0[5];
    o1.z = s[6]  * (float)v0[6]; o1.w = s[7]  * (float)v0[7];
    o2.x = s[8]  * (float)v1[0]; o2.y = s[9]  * (float)v1[1];
    o2.z = s[10] * (float)v1[2]; o2.w = s[11] * (float)v1[3];
    o3.x = s[12] * (float)v1[4]; o3.y = s[13] * (float)v1[5];
    o3.z = s[14] * (float)v1[6]; o3.w = s[15] * (float)v1[7];
    *reinterpret_cast<float4*>(op)      = o0;
    *reinterpret_cast<float4*>(op + 4)  = o1;
    *reinterpret_cast<float4*>(op + 8)  = o2;
    *reinterpret_cast<float4*>(op + 12) = o3;
}

// ---------------------------------------------------------------------------
extern "C" void kernel_launch(void* const* d_in, const int* in_sizes, int n_in,
                              void* d_out, int out_size, void* d_ws, size_t ws_size,
                              hipStream_t stream) {
    const float* hs = (const float*)d_in[0];  // [65536,512]
    const float* w  = (const float*)d_in[1];  // [1536,512]
    const float* bq = (const float*)d_in[2];  // [1536]
    float* out = (float*)d_out;
    _Float16* qkv = (_Float16*)d_ws;          // 201,326,592 B (fits)

    // d_out as scratch: Af (67,108,864 B) | Wf (1,572,864 B)
    _Float16* Af = (_Float16*)d_out;
    _Float16* Wf = Af + 33554432;             // 65536*512

    cvt_a_frag<<<16384, 256, 0, stream>>>(hs, Af);
    cvt_w_frag<<<384, 256, 0, stream>>>(w, Wf);
    gemm_nolds<<<6144, 256, 0, stream>>>(Af, Wf, bq, qkv);
    attn_scramble<<<8192, 256, 0, stream>>>(qkv, out);
}

// Round 27
// 231.294 us; speedup vs baseline: 1.4436x; 1.0117x over previous
//
#include <hip/hip_runtime.h>
#include <math.h>

// Pipeline (d_out doubles as scratch: Af fp16 67MB + Wf fp16 1.5MB):
//   k0 cvt_a_frag:  A fp32 -> Af fp16 in MFMA FRAGMENT order
//   k0b cvt_w_frag: w_qkv fp32 -> Wf fp16 in FRAGMENT order
//   k1 gemm:        qkv16 = fp16(Af @ W^T + bias) in d_ws.
//                   r27: no-LDS loop, WAVE TILE 128x64 (block 256x128,
//                   2M x 2N waves). 12KB loads per 32 MFMA = 375 B/MFMA
//                   (vs r26's 512) -> less L2 traffic, 2x MFMA per load
//                   batch. launch_bounds(256,2): ~240 regs < 256 budget.
//   k2 scramble:    qkv16 -> out fp32 (r18-verified)

typedef _Float16 half8 __attribute__((ext_vector_type(8)));
typedef _Float16 half4 __attribute__((ext_vector_type(4)));
typedef __fp16 fp16x2 __attribute__((ext_vector_type(2)));
typedef float f32x4 __attribute__((ext_vector_type(4)));

__device__ __forceinline__ half8 pk8(const float4 x, const float4 y) {
    fp16x2 a = __builtin_amdgcn_cvt_pkrtz(x.x, x.y);
    fp16x2 b = __builtin_amdgcn_cvt_pkrtz(x.z, x.w);
    fp16x2 c = __builtin_amdgcn_cvt_pkrtz(y.x, y.y);
    fp16x2 d = __builtin_amdgcn_cvt_pkrtz(y.z, y.w);
    half8 r;
    r[0] = (_Float16)a[0]; r[1] = (_Float16)a[1];
    r[2] = (_Float16)b[0]; r[3] = (_Float16)b[1];
    r[4] = (_Float16)c[0]; r[5] = (_Float16)c[1];
    r[6] = (_Float16)d[0]; r[7] = (_Float16)d[1];
    return r;
}

// ---------------------------------------------------------------------------
// k0: A fp32 [65536,512] -> Af fp16 fragment-ordered.
// Af[((gm*16+ks)*64+lane)*8+e] = A[gm*16+(lane&15)][ks*32+(lane>>4)*8+e]
// ---------------------------------------------------------------------------
__global__ __launch_bounds__(256) void cvt_a_frag(
    const float* __restrict__ A, _Float16* __restrict__ Af)
{
    const int gid  = blockIdx.x * 256 + threadIdx.x;
    const int lane = gid & 63;
    const int ks   = (gid >> 6) & 15;
    const int gm   = gid >> 10;
    const float* src =
        A + (size_t)(gm * 16 + (lane & 15)) * 512 + ks * 32 + (lane >> 4) * 8;
    const float4 x = *reinterpret_cast<const float4*>(src);
    const float4 y = *reinterpret_cast<const float4*>(src + 4);
    *reinterpret_cast<half8*>(Af + (size_t)gid * 8) = pk8(x, y);
}

// ---------------------------------------------------------------------------
// k0b: W fp32 [1536,512] -> Wf fp16 fragment-ordered (98304 threads)
// ---------------------------------------------------------------------------
__global__ __launch_bounds__(256) void cvt_w_frag(
    const float* __restrict__ W, _Float16* __restrict__ Wf)
{
    const int gid  = blockIdx.x * 256 + threadIdx.x;   // 0..98303
    const int lane = gid & 63;
    const int nf   = (gid >> 6) & 3;
    const int ks   = (gid >> 8) & 15;
    const int ntw  = gid >> 12;                        // 0..23
    const float* src =
        W + (size_t)(ntw * 64 + nf * 16 + (lane & 15)) * 512 +
        ks * 32 + (lane >> 4) * 8;
    const float4 x = *reinterpret_cast<const float4*>(src);
    const float4 y = *reinterpret_cast<const float4*>(src + 4);
    *reinterpret_cast<half8*>(Wf + (size_t)gid * 8) = pk8(x, y);
}

// ---------------------------------------------------------------------------
// k1: C16[65536,1536] = fp16(Af @ W^T + bias).  Block 256x128, 4 waves
// (2M x 2N), wave tile 128x64. NO LDS in main loop (epilogue only).
// A-frag mf (0..7) at K-tile T: Af + (row0/16 + wm*8 + mf)*8192 + T*512 + lane*8
// W-frag nf (0..3) at K-tile T: Wf + (nt*2+wn)*32768 + T*2048 + nf*512 + lane*8
// ---------------------------------------------------------------------------
__global__ __launch_bounds__(256, 2) void gemm_nolds2(
    const _Float16* __restrict__ Af, const _Float16* __restrict__ Wf,
    const float* __restrict__ bias, _Float16* __restrict__ C)
{
    __shared__ __align__(16) float eplds[4352];     // 17.4 KB, epilogue only

    const int lin = blockIdx.x;                     // 3072 blocks, %8==0
    const int swz = (lin & 7) * 384 + (lin >> 3);
    const int nt = swz % 12, mt = swz / 12;         // nt fastest: A L2-reuse
    const int row0 = mt * 256, col0 = nt * 128;

    const int tid = threadIdx.x, wid = tid >> 6, lane = tid & 63;
    const int wm = wid >> 1, wn = wid & 1, l15 = lane & 15, kq = lane >> 4;

    const _Float16* pAf = Af + (size_t)(row0 / 16 + wm * 8) * 8192 + lane * 8;
    const _Float16* pW  = Wf + (size_t)(nt * 2 + wn) * 32768 + lane * 8;

    f32x4 acc[8][4];
#pragma unroll
    for (int i = 0; i < 8; ++i)
#pragma unroll
        for (int j = 0; j < 4; ++j) acc[i][j] = (f32x4)0.f;

    half8 aA[8], aB[8], wA[4], wB[4];   // two named A/W register sets

#define LOADA(DST, T)                                                          \
    do {                                                                       \
        _Pragma("unroll")                                                      \
        for (int mf = 0; mf < 8; ++mf)                                         \
            DST[mf] = *reinterpret_cast<const half8*>(                         \
                pAf + mf * 8192 + (T) * 512);                                  \
    } while (0)

#define LOADW(DST, T)                                                          \
    do {                                                                       \
        _Pragma("unroll")                                                      \
        for (int nf = 0; nf < 4; ++nf)                                         \
            DST[nf] = *reinterpret_cast<const half8*>(                         \
                pW + (T) * 2048 + nf * 512);                                   \
    } while (0)

#define FRAG(AS, WS)                                                           \
    do {                                                                       \
        __builtin_amdgcn_s_setprio(1);                                         \
        _Pragma("unroll")                                                      \
        for (int nf = 0; nf < 4; ++nf)                                         \
            _Pragma("unroll")                                                  \
            for (int mf = 0; mf < 8; ++mf)                                     \
                acc[mf][nf] = __builtin_amdgcn_mfma_f32_16x16x32_f16(          \
                    AS[mf], WS[nf], acc[mf][nf], 0, 0, 0);                     \
        __builtin_amdgcn_s_setprio(0);                                         \
    } while (0)

    // prologue: sets A<-tile0, B<-tile1
    LOADA(aA, 0); LOADW(wA, 0);
    LOADA(aB, 1); LOADW(wB, 1);

#pragma unroll
    for (int t = 0; t < 16; t += 2) {
        FRAG(aA, wA);
        if (t + 2 < 16) { LOADA(aA, t + 2); LOADW(wA, t + 2); }
        FRAG(aB, wB);
        if (t + 3 < 16) { LOADA(aB, t + 3); LOADW(wB, t + 3); }
    }
#undef FRAG
#undef LOADW
#undef LOADA

    // ---- epilogue: per-wave LDS transpose -> fp16 half4 stores.
    // __syncthreads() fences between scatter and gather (r17-verified).
    float* wbase = eplds + wid * 1088;
    const float4 bv4 = *reinterpret_cast<const float4*>(
        &bias[col0 + wn * 64 + l15 * 4]);

#pragma unroll
    for (int mf = 0; mf < 8; ++mf) {
#pragma unroll
        for (int nf = 0; nf < 4; ++nf)
#pragma unroll
            for (int j = 0; j < 4; ++j)
                wbase[(kq * 4 + j) * 68 + nf * 16 + l15] = acc[mf][nf][j];
        __syncthreads();   // writes visible before cross-lane reads
#pragma unroll
        for (int i = 0; i < 4; ++i) {
            const int r16 = i * 4 + kq;
            float4 v = *reinterpret_cast<float4*>(wbase + r16 * 68 + l15 * 4);
            half4 h;
            h[0] = (_Float16)(v.x + bv4.x);   // RNE
            h[1] = (_Float16)(v.y + bv4.y);
            h[2] = (_Float16)(v.z + bv4.z);
            h[3] = (_Float16)(v.w + bv4.w);
            const int r = row0 + wm * 128 + mf * 16 + r16;
            *reinterpret_cast<half4*>(
                &C[(size_t)r * 1536 + col0 + wn * 64 + l15 * 4]) = h;
        }
        __syncthreads();   // reads done before next mf's scatter overwrites
    }
}

// ---------------------------------------------------------------------------
// k2: scrambled elementwise softmax; qkv FP16 (r18-verified)
// ---------------------------------------------------------------------------
__global__ __launch_bounds__(256) void attn_scramble(
    const _Float16* __restrict__ qkv, float* __restrict__ out)
{
    __shared__ float Ks[64][68];    // [hwlo][d'], rows 272B (16B-aligned)
    const int bid = blockIdx.x;
    const int hw6 = bid & 63;
    const int n   = (bid >> 6) & 7;
    const int b   = bid >> 9;
    const int kn  = (n + 7) & 7;
    const int t   = threadIdx.x;
    {
        const int lx = t & 7;       // 8 lanes x half8 cover one d'-row (64)
        const int rp = t >> 3;      // 32 d'-rows per pass
#pragma unroll
        for (int p = 0; p < 2; ++p) {
            const int dp = p * 32 + rp;
            const half8 kv = *reinterpret_cast<const half8*>(
                &qkv[(size_t)(b * 4096 + dp * 64 + hw6) * 1536 + 512 +
                     kn * 64 + lx * 8]);
#pragma unroll
            for (int e = 0; e < 8; ++e)
                Ks[lx * 8 + e][dp] = (float)kv[e];
        }
    }
    __syncthreads();
    const int row = t >> 2;
    const int tl  = t & 3;
    const size_t rbase = (size_t)(b * 4096 + hw6 * 64 + row) * 1536;
    float s[16];
    {
        const _Float16* qp = qkv + rbase + n * 64 + tl * 16;
        const half8 q0 = *reinterpret_cast<const half8*>(qp);
        const half8 q1 = *reinterpret_cast<const half8*>(qp + 8);
        float q[16], kk[16];
#pragma unroll
        for (int e = 0; e < 8; ++e) {
            q[e] = (float)q0[e];
            q[8 + e] = (float)q1[e];
        }
#pragma unroll
        for (int u = 0; u < 4; ++u)
            *reinterpret_cast<float4*>(&kk[u * 4]) =
                *reinterpret_cast<const float4*>(&Ks[row][tl * 16 + u * 4]);
        float m = -1e30f;
#pragma unroll
        for (int u = 0; u < 16; ++u) {
            s[u] = 0.125f * q[u] * kk[u];
            m = fmaxf(m, s[u]);
        }
        m = fmaxf(m, __shfl_xor(m, 1));
        m = fmaxf(m, __shfl_xor(m, 2));
        float sum = 0.f;
#pragma unroll
        for (int u = 0; u < 16; ++u) {
            s[u] = __expf(s[u] - m);
            sum += s[u];
        }
        sum += __shfl_xor(sum, 1);
        sum += __shfl_xor(sum, 2);
        const float inv = 1.0f / sum;
#pragma unroll
        for (int u = 0; u < 16; ++u) s[u] *= inv;
    }
    const _Float16* vp = qkv + rbase + 1024 + kn * 64 + tl * 16;
    const half8 v0 = *reinterpret_cast<const half8*>(vp);
    const half8 v1 = *reinterpret_cast<const half8*>(vp + 8);
    const int vb = b >> 3, fr = b & 7;
    float* op = out +
        ((size_t)(((vb * 8 + (hw6 >> 3)) * 64 + ((hw6 & 7) * 8 + (row >> 3))) * 64 +
                  ((row & 7) * 8 + n)) * 512) + fr * 64 + tl * 16;
    float4 o0, o1, o2, o3;
    o0.x = s[0]  * (float)v0[0]; o0.y = s[1]  * (float)v0[1];
    o0.z = s[2]  * (float)v0[2]; o0.w = s[3]  * (float)v0[3];
    o1.x = s[4]  * (float)v0[4]; o1.y = s[5]  * (float)v0[5];
    o1.z = s[6]  * (float)v0[6]; o1.w = s[7]  * (float)v0[7];
    o2.x = s[8]  * (float)v1[0]; o2.y = s[9]  * (float)v1[1];
    o2.z = s[10] * (float)v1[2]; o2.w = s[11] * (float)v1[3];
    o3.x = s[12] * (float)v1[4]; o3.y = s[13] * (float)v1[5];
    o3.z = s[14] * (float)v1[6]; o3.w = s[15] * (float)v1[7];
    *reinterpret_cast<float4*>(op)      = o0;
    *reinterpret_cast<float4*>(op + 4)  = o1;
    *reinterpret_cast<float4*>(op + 8)  = o2;
    *reinterpret_cast<float4*>(op + 12) = o3;
}

// ---------------------------------------------------------------------------
extern "C" void kernel_launch(void* const* d_in, const int* in_sizes, int n_in,
                              void* d_out, int out_size, void* d_ws, size_t ws_size,
                              hipStream_t stream) {
    const float* hs = (const float*)d_in[0];  // [65536,512]
    const float* w  = (const float*)d_in[1];  // [1536,512]
    const float* bq = (const float*)d_in[2];  // [1536]
    float* out = (float*)d_out;
    _Float16* qkv = (_Float16*)d_ws;          // 201,326,592 B (fits)

    // d_out as scratch: Af (67,108,864 B) | Wf (1,572,864 B)
    _Float16* Af = (_Float16*)d_out;
    _Float16* Wf = Af + 33554432;             // 65536*512

    cvt_a_frag<<<16384, 256, 0, stream>>>(hs, Af);
    cvt_w_frag<<<384, 256, 0, stream>>>(w, Wf);
    gemm_nolds2<<<3072, 256, 0, stream>>>(Af, Wf, bq, qkv);
    attn_scramble<<<8192, 256, 0, stream>>>(qkv, out);
}

// Round 28
// 226.050 us; speedup vs baseline: 1.4771x; 1.0232x over previous
//
#include <hip/hip_runtime.h>
#include <math.h>

// Pipeline (d_out doubles as scratch: Af fp16 67MB + Wf fp16 1.5MB):
//   k0 cvt_a_frag:  A fp32 -> Af fp16 in MFMA FRAGMENT order
//   k0b cvt_w_frag: w_qkv fp32 -> Wf fp16 in FRAGMENT order
//   k1 gemm:        qkv16 = fp16(Af @ W^T + bias) in d_ws.
//                   r28: r27 (no-LDS, 128x64 wave tile, block 256x128) with
//                   A prefetch depth-1 (ONE 8-frag set) — r27's two A sets
//                   hit the 256-reg budget and spilled ~25MB (WRITE 221 vs
//                   197). ~212 regs now; 8 free-running waves/CU hide the
//                   A-load L2 latency.
//   k2 scramble:    qkv16 -> out fp32 (r18-verified)

typedef _Float16 half8 __attribute__((ext_vector_type(8)));
typedef _Float16 half4 __attribute__((ext_vector_type(4)));
typedef __fp16 fp16x2 __attribute__((ext_vector_type(2)));
typedef float f32x4 __attribute__((ext_vector_type(4)));

__device__ __forceinline__ half8 pk8(const float4 x, const float4 y) {
    fp16x2 a = __builtin_amdgcn_cvt_pkrtz(x.x, x.y);
    fp16x2 b = __builtin_amdgcn_cvt_pkrtz(x.z, x.w);
    fp16x2 c = __builtin_amdgcn_cvt_pkrtz(y.x, y.y);
    fp16x2 d = __builtin_amdgcn_cvt_pkrtz(y.z, y.w);
    half8 r;
    r[0] = (_Float16)a[0]; r[1] = (_Float16)a[1];
    r[2] = (_Float16)b[0]; r[3] = (_Float16)b[1];
    r[4] = (_Float16)c[0]; r[5] = (_Float16)c[1];
    r[6] = (_Float16)d[0]; r[7] = (_Float16)d[1];
    return r;
}

// ---------------------------------------------------------------------------
// k0: A fp32 [65536,512] -> Af fp16 fragment-ordered.
// Af[((gm*16+ks)*64+lane)*8+e] = A[gm*16+(lane&15)][ks*32+(lane>>4)*8+e]
// ---------------------------------------------------------------------------
__global__ __launch_bounds__(256) void cvt_a_frag(
    const float* __restrict__ A, _Float16* __restrict__ Af)
{
    const int gid  = blockIdx.x * 256 + threadIdx.x;
    const int lane = gid & 63;
    const int ks   = (gid >> 6) & 15;
    const int gm   = gid >> 10;
    const float* src =
        A + (size_t)(gm * 16 + (lane & 15)) * 512 + ks * 32 + (lane >> 4) * 8;
    const float4 x = *reinterpret_cast<const float4*>(src);
    const float4 y = *reinterpret_cast<const float4*>(src + 4);
    *reinterpret_cast<half8*>(Af + (size_t)gid * 8) = pk8(x, y);
}

// ---------------------------------------------------------------------------
// k0b: W fp32 [1536,512] -> Wf fp16 fragment-ordered (98304 threads)
// ---------------------------------------------------------------------------
__global__ __launch_bounds__(256) void cvt_w_frag(
    const float* __restrict__ W, _Float16* __restrict__ Wf)
{
    const int gid  = blockIdx.x * 256 + threadIdx.x;   // 0..98303
    const int lane = gid & 63;
    const int nf   = (gid >> 6) & 3;
    const int ks   = (gid >> 8) & 15;
    const int ntw  = gid >> 12;                        // 0..23
    const float* src =
        W + (size_t)(ntw * 64 + nf * 16 + (lane & 15)) * 512 +
        ks * 32 + (lane >> 4) * 8;
    const float4 x = *reinterpret_cast<const float4*>(src);
    const float4 y = *reinterpret_cast<const float4*>(src + 4);
    *reinterpret_cast<half8*>(Wf + (size_t)gid * 8) = pk8(x, y);
}

// ---------------------------------------------------------------------------
// k1: C16[65536,1536] = fp16(Af @ W^T + bias).  Block 256x128, 4 waves
// (2M x 2N), wave tile 128x64. NO LDS in main loop (epilogue only).
// A-frag mf (0..7) at K-tile T: Af + (row0/16 + wm*8 + mf)*8192 + T*512 + lane*8
// W-frag nf (0..3) at K-tile T: Wf + (nt*2+wn)*32768 + T*2048 + nf*512 + lane*8
// ---------------------------------------------------------------------------
__global__ __launch_bounds__(256, 2) void gemm_nolds3(
    const _Float16* __restrict__ Af, const _Float16* __restrict__ Wf,
    const float* __restrict__ bias, _Float16* __restrict__ C)
{
    __shared__ __align__(16) float eplds[4352];     // 17.4 KB, epilogue only

    const int lin = blockIdx.x;                     // 3072 blocks, %8==0
    const int swz = (lin & 7) * 384 + (lin >> 3);
    const int nt = swz % 12, mt = swz / 12;         // nt fastest: A L2-reuse
    const int row0 = mt * 256, col0 = nt * 128;

    const int tid = threadIdx.x, wid = tid >> 6, lane = tid & 63;
    const int wm = wid >> 1, wn = wid & 1, l15 = lane & 15, kq = lane >> 4;

    const _Float16* pAf = Af + (size_t)(row0 / 16 + wm * 8) * 8192 + lane * 8;
    const _Float16* pW  = Wf + (size_t)(nt * 2 + wn) * 32768 + lane * 8;

    f32x4 acc[8][4];
#pragma unroll
    for (int i = 0; i < 8; ++i)
#pragma unroll
        for (int j = 0; j < 4; ++j) acc[i][j] = (f32x4)0.f;

    half8 aS[8], wA[4], wB[4];   // ONE A set (depth-1), two W sets

#define LOADA(T)                                                               \
    do {                                                                       \
        _Pragma("unroll")                                                      \
        for (int mf = 0; mf < 8; ++mf)                                         \
            aS[mf] = *reinterpret_cast<const half8*>(                          \
                pAf + mf * 8192 + (T) * 512);                                  \
    } while (0)

#define LOADW(DST, T)                                                          \
    do {                                                                       \
        _Pragma("unroll")                                                      \
        for (int nf = 0; nf < 4; ++nf)                                         \
            DST[nf] = *reinterpret_cast<const half8*>(                         \
                pW + (T) * 2048 + nf * 512);                                   \
    } while (0)

#define FRAG(WS)                                                               \
    do {                                                                       \
        __builtin_amdgcn_s_setprio(1);                                         \
        _Pragma("unroll")                                                      \
        for (int nf = 0; nf < 4; ++nf)                                         \
            _Pragma("unroll")                                                  \
            for (int mf = 0; mf < 8; ++mf)                                     \
                acc[mf][nf] = __builtin_amdgcn_mfma_f32_16x16x32_f16(          \
                    aS[mf], WS[nf], acc[mf][nf], 0, 0, 0);                     \
        __builtin_amdgcn_s_setprio(0);                                         \
    } while (0)

    // prologue
    LOADA(0);
    LOADW(wA, 0);
    LOADW(wB, 1);

#pragma unroll
    for (int t = 0; t < 16; t += 2) {
        FRAG(wA);                               // consumes aS (tile t)
        LOADA(t + 1);                           // refill aS (WAR ok at issue)
        if (t + 2 < 16) LOADW(wA, t + 2);
        FRAG(wB);                               // consumes aS (tile t+1)
        if (t + 2 < 16) LOADA(t + 2);
        if (t + 3 < 16) LOADW(wB, t + 3);
    }
#undef FRAG
#undef LOADW
#undef LOADA

    // ---- epilogue: per-wave LDS transpose -> fp16 half4 stores.
    // __syncthreads() fences between scatter and gather (r17-verified).
    float* wbase = eplds + wid * 1088;
    const float4 bv4 = *reinterpret_cast<const float4*>(
        &bias[col0 + wn * 64 + l15 * 4]);

#pragma unroll
    for (int mf = 0; mf < 8; ++mf) {
#pragma unroll
        for (int nf = 0; nf < 4; ++nf)
#pragma unroll
            for (int j = 0; j < 4; ++j)
                wbase[(kq * 4 + j) * 68 + nf * 16 + l15] = acc[mf][nf][j];
        __syncthreads();   // writes visible before cross-lane reads
#pragma unroll
        for (int i = 0; i < 4; ++i) {
            const int r16 = i * 4 + kq;
            float4 v = *reinterpret_cast<float4*>(wbase + r16 * 68 + l15 * 4);
            half4 h;
            h[0] = (_Float16)(v.x + bv4.x);   // RNE
            h[1] = (_Float16)(v.y + bv4.y);
            h[2] = (_Float16)(v.z + bv4.z);
            h[3] = (_Float16)(v.w + bv4.w);
            const int r = row0 + wm * 128 + mf * 16 + r16;
            *reinterpret_cast<half4*>(
                &C[(size_t)r * 1536 + col0 + wn * 64 + l15 * 4]) = h;
        }
        __syncthreads();   // reads done before next mf's scatter overwrites
    }
}

// ---------------------------------------------------------------------------
// k2: scrambled elementwise softmax; qkv FP16 (r18-verified)
// ---------------------------------------------------------------------------
__global__ __launch_bounds__(256) void attn_scramble(
    const _Float16* __restrict__ qkv, float* __restrict__ out)
{
    __shared__ float Ks[64][68];    // [hwlo][d'], rows 272B (16B-aligned)
    const int bid = blockIdx.x;
    const int hw6 = bid & 63;
    const int n   = (bid >> 6) & 7;
    const int b   = bid >> 9;
    const int kn  = (n + 7) & 7;
    const int t   = threadIdx.x;
    {
        const int lx = t & 7;       // 8 lanes x half8 cover one d'-row (64)
        const int rp = t >> 3;      // 32 d'-rows per pass
#pragma unroll
        for (int p = 0; p < 2; ++p) {
            const int dp = p * 32 + rp;
            const half8 kv = *reinterpret_cast<const half8*>(
                &qkv[(size_t)(b * 4096 + dp * 64 + hw6) * 1536 + 512 +
                     kn * 64 + lx * 8]);
#pragma unroll
            for (int e = 0; e < 8; ++e)
                Ks[lx * 8 + e][dp] = (float)kv[e];
        }
    }
    __syncthreads();
    const int row = t >> 2;
    const int tl  = t & 3;
    const size_t rbase = (size_t)(b * 4096 + hw6 * 64 + row) * 1536;
    float s[16];
    {
        const _Float16* qp = qkv + rbase + n * 64 + tl * 16;
        const half8 q0 = *reinterpret_cast<const half8*>(qp);
        const half8 q1 = *reinterpret_cast<const half8*>(qp + 8);
        float q[16], kk[16];
#pragma unroll
        for (int e = 0; e < 8; ++e) {
            q[e] = (float)q0[e];
            q[8 + e] = (float)q1[e];
        }
#pragma unroll
        for (int u = 0; u < 4; ++u)
            *reinterpret_cast<float4*>(&kk[u * 4]) =
                *reinterpret_cast<const float4*>(&Ks[row][tl * 16 + u * 4]);
        float m = -1e30f;
#pragma unroll
        for (int u = 0; u < 16; ++u) {
            s[u] = 0.125f * q[u] * kk[u];
            m = fmaxf(m, s[u]);
        }
        m = fmaxf(m, __shfl_xor(m, 1));
        m = fmaxf(m, __shfl_xor(m, 2));
        float sum = 0.f;
#pragma unroll
        for (int u = 0; u < 16; ++u) {
            s[u] = __expf(s[u] - m);
            sum += s[u];
        }
        sum += __shfl_xor(sum, 1);
        sum += __shfl_xor(sum, 2);
        const float inv = 1.0f / sum;
#pragma unroll
        for (int u = 0; u < 16; ++u) s[u] *= inv;
    }
    const _Float16* vp = qkv + rbase + 1024 + kn * 64 + tl * 16;
    const half8 v0 = *reinterpret_cast<const half8*>(vp);
    const half8 v1 = *reinterpret_cast<const half8*>(vp + 8);
    const int vb = b >> 3, fr = b & 7;
    float* op = out +
        ((size_t)(((vb * 8 + (hw6 >> 3)) * 64 + ((hw6 & 7) * 8 + (row >> 3))) * 64 +
                  ((row & 7) * 8 + n)) * 512) + fr * 64 + tl * 16;
    float4 o0, o1, o2, o3;
    o0.x = s[0]  * (float)v0[0]; o0.y = s[1]  * (float)v0[1];
    o0.z = s[2]  * (float)v0[2]; o0.w = s[3]  * (float)v0[3];
    o1.x = s[4]  * (float)v0[4]; o1.y = s[5]  * (float)v0[5];
    o1.z = s[6]  * (float)v0[6]; o1.w = s[7]  * (float)v0[7];
    o2.x = s[8]  * (float)v1[0]; o2.y = s[9]  * (float)v1[1];
    o2.z = s[10] * (float)v1[2]; o2.w = s[11] * (float)v1[3];
    o3.x = s[12] * (float)v1[4]; o3.y = s[13] * (float)v1[5];
    o3.z = s[14] * (float)v1[6]; o3.w = s[15] * (float)v1[7];
    *reinterpret_cast<float4*>(op)      = o0;
    *reinterpret_cast<float4*>(op + 4)  = o1;
    *reinterpret_cast<float4*>(op + 8)  = o2;
    *reinterpret_cast<float4*>(op + 12) = o3;
}

// ---------------------------------------------------------------------------
extern "C" void kernel_launch(void* const* d_in, const int* in_sizes, int n_in,
                              void* d_out, int out_size, void* d_ws, size_t ws_size,
                              hipStream_t stream) {
    const float* hs = (const float*)d_in[0];  // [65536,512]
    const float* w  = (const float*)d_in[1];  // [1536,512]
    const float* bq = (const float*)d_in[2];  // [1536]
    float* out = (float*)d_out;
    _Float16* qkv = (_Float16*)d_ws;          // 201,326,592 B (fits)

    // d_out as scratch: Af (67,108,864 B) | Wf (1,572,864 B)
    _Float16* Af = (_Float16*)d_out;
    _Float16* Wf = Af + 33554432;             // 65536*512

    cvt_a_frag<<<16384, 256, 0, stream>>>(hs, Af);
    cvt_w_frag<<<384, 256, 0, stream>>>(w, Wf);
    gemm_nolds3<<<3072, 256, 0, stream>>>(Af, Wf, bq, qkv);
    attn_scramble<<<8192, 256, 0, stream>>>(qkv, out);
}

// Round 29
// 221.938 us; speedup vs baseline: 1.5044x; 1.0185x over previous
//
#include <hip/hip_runtime.h>
#include <math.h>

// Pipeline (d_out doubles as scratch: Af fp16 67MB + Wf fp16 1.5MB):
//   k0 cvt_a_frag:  A fp32 -> Af fp16 in MFMA FRAGMENT order
//   k0b cvt_w_frag: w_qkv fp32 -> Wf fp16 in FRAGMENT order
//   k1 gemm:        qkv16 = fp16(Af @ W^T + bias) in d_ws.
//                   r29: r28 (no-LDS, 128x64 wave tile) with the A set split
//                   LO/HI and pipelined at half-tile granularity — each
//                   A-load now has >=16 MFMA own-wave cover (r28 had ~0).
//                   Same register count as r28 (no spill risk).
//   k2 scramble:    qkv16 -> out fp32 (r18-verified)

typedef _Float16 half8 __attribute__((ext_vector_type(8)));
typedef _Float16 half4 __attribute__((ext_vector_type(4)));
typedef __fp16 fp16x2 __attribute__((ext_vector_type(2)));
typedef float f32x4 __attribute__((ext_vector_type(4)));

__device__ __forceinline__ half8 pk8(const float4 x, const float4 y) {
    fp16x2 a = __builtin_amdgcn_cvt_pkrtz(x.x, x.y);
    fp16x2 b = __builtin_amdgcn_cvt_pkrtz(x.z, x.w);
    fp16x2 c = __builtin_amdgcn_cvt_pkrtz(y.x, y.y);
    fp16x2 d = __builtin_amdgcn_cvt_pkrtz(y.z, y.w);
    half8 r;
    r[0] = (_Float16)a[0]; r[1] = (_Float16)a[1];
    r[2] = (_Float16)b[0]; r[3] = (_Float16)b[1];
    r[4] = (_Float16)c[0]; r[5] = (_Float16)c[1];
    r[6] = (_Float16)d[0]; r[7] = (_Float16)d[1];
    return r;
}

// ---------------------------------------------------------------------------
// k0: A fp32 [65536,512] -> Af fp16 fragment-ordered.
// Af[((gm*16+ks)*64+lane)*8+e] = A[gm*16+(lane&15)][ks*32+(lane>>4)*8+e]
// ---------------------------------------------------------------------------
__global__ __launch_bounds__(256) void cvt_a_frag(
    const float* __restrict__ A, _Float16* __restrict__ Af)
{
    const int gid  = blockIdx.x * 256 + threadIdx.x;
    const int lane = gid & 63;
    const int ks   = (gid >> 6) & 15;
    const int gm   = gid >> 10;
    const float* src =
        A + (size_t)(gm * 16 + (lane & 15)) * 512 + ks * 32 + (lane >> 4) * 8;
    const float4 x = *reinterpret_cast<const float4*>(src);
    const float4 y = *reinterpret_cast<const float4*>(src + 4);
    *reinterpret_cast<half8*>(Af + (size_t)gid * 8) = pk8(x, y);
}

// ---------------------------------------------------------------------------
// k0b: W fp32 [1536,512] -> Wf fp16 fragment-ordered (98304 threads)
// ---------------------------------------------------------------------------
__global__ __launch_bounds__(256) void cvt_w_frag(
    const float* __restrict__ W, _Float16* __restrict__ Wf)
{
    const int gid  = blockIdx.x * 256 + threadIdx.x;   // 0..98303
    const int lane = gid & 63;
    const int nf   = (gid >> 6) & 3;
    const int ks   = (gid >> 8) & 15;
    const int ntw  = gid >> 12;                        // 0..23
    const float* src =
        W + (size_t)(ntw * 64 + nf * 16 + (lane & 15)) * 512 +
        ks * 32 + (lane >> 4) * 8;
    const float4 x = *reinterpret_cast<const float4*>(src);
    const float4 y = *reinterpret_cast<const float4*>(src + 4);
    *reinterpret_cast<half8*>(Wf + (size_t)gid * 8) = pk8(x, y);
}

// ---------------------------------------------------------------------------
// k1: C16[65536,1536] = fp16(Af @ W^T + bias).  Block 256x128, 4 waves
// (2M x 2N), wave tile 128x64. NO LDS in main loop (epilogue only).
// A-frag mf (0..7) at K-tile T: Af + (row0/16 + wm*8 + mf)*8192 + T*512 + lane*8
// W-frag nf (0..3) at K-tile T: Wf + (nt*2+wn)*32768 + T*2048 + nf*512 + lane*8
// ---------------------------------------------------------------------------
__global__ __launch_bounds__(256, 2) void gemm_nolds4(
    const _Float16* __restrict__ Af, const _Float16* __restrict__ Wf,
    const float* __restrict__ bias, _Float16* __restrict__ C)
{
    __shared__ __align__(16) float eplds[4352];     // 17.4 KB, epilogue only

    const int lin = blockIdx.x;                     // 3072 blocks, %8==0
    const int swz = (lin & 7) * 384 + (lin >> 3);
    const int nt = swz % 12, mt = swz / 12;         // nt fastest: A L2-reuse
    const int row0 = mt * 256, col0 = nt * 128;

    const int tid = threadIdx.x, wid = tid >> 6, lane = tid & 63;
    const int wm = wid >> 1, wn = wid & 1, l15 = lane & 15, kq = lane >> 4;

    const _Float16* pAf = Af + (size_t)(row0 / 16 + wm * 8) * 8192 + lane * 8;
    const _Float16* pW  = Wf + (size_t)(nt * 2 + wn) * 32768 + lane * 8;

    f32x4 acc[8][4];
#pragma unroll
    for (int i = 0; i < 8; ++i)
#pragma unroll
        for (int j = 0; j < 4; ++j) acc[i][j] = (f32x4)0.f;

    half8 aLo[4], aHi[4], wA[4], wB[4];   // A split LO/HI; two W sets

#define LOADA_LO(T)                                                            \
    do {                                                                       \
        _Pragma("unroll")                                                      \
        for (int mf = 0; mf < 4; ++mf)                                         \
            aLo[mf] = *reinterpret_cast<const half8*>(                         \
                pAf + mf * 8192 + (T) * 512);                                  \
    } while (0)

#define LOADA_HI(T)                                                            \
    do {                                                                       \
        _Pragma("unroll")                                                      \
        for (int mf = 0; mf < 4; ++mf)                                         \
            aHi[mf] = *reinterpret_cast<const half8*>(                         \
                pAf + (mf + 4) * 8192 + (T) * 512);                            \
    } while (0)

#define LOADW(DST, T)                                                          \
    do {                                                                       \
        _Pragma("unroll")                                                      \
        for (int nf = 0; nf < 4; ++nf)                                         \
            DST[nf] = *reinterpret_cast<const half8*>(                         \
                pW + (T) * 2048 + nf * 512);                                   \
    } while (0)

#define FRAG_LO(WS)                                                            \
    do {                                                                       \
        __builtin_amdgcn_s_setprio(1);                                         \
        _Pragma("unroll")                                                      \
        for (int nf = 0; nf < 4; ++nf)                                         \
            _Pragma("unroll")                                                  \
            for (int mf = 0; mf < 4; ++mf)                                     \
                acc[mf][nf] = __builtin_amdgcn_mfma_f32_16x16x32_f16(          \
                    aLo[mf], WS[nf], acc[mf][nf], 0, 0, 0);                    \
        __builtin_amdgcn_s_setprio(0);                                         \
    } while (0)

#define FRAG_HI(WS)                                                            \
    do {                                                                       \
        __builtin_amdgcn_s_setprio(1);                                         \
        _Pragma("unroll")                                                      \
        for (int nf = 0; nf < 4; ++nf)                                         \
            _Pragma("unroll")                                                  \
            for (int mf = 0; mf < 4; ++mf)                                     \
                acc[mf + 4][nf] = __builtin_amdgcn_mfma_f32_16x16x32_f16(      \
                    aHi[mf], WS[nf], acc[mf + 4][nf], 0, 0, 0);                \
        __builtin_amdgcn_s_setprio(0);                                         \
    } while (0)

    // prologue
    LOADA_LO(0); LOADA_HI(0);
    LOADW(wA, 0); LOADW(wB, 1);

#pragma unroll
    for (int t = 0; t < 16; t += 2) {
        FRAG_LO(wA);                              // aLo(t)
        LOADA_LO(t + 1);                          // covered by FRAG_HI below
        FRAG_HI(wA);                              // aHi(t)
        LOADA_HI(t + 1);
        if (t + 2 < 16) LOADW(wA, t + 2);
        FRAG_LO(wB);                              // aLo(t+1)
        if (t + 2 < 16) LOADA_LO(t + 2);
        FRAG_HI(wB);                              // aHi(t+1)
        if (t + 2 < 16) LOADA_HI(t + 2);
        if (t + 3 < 16) LOADW(wB, t + 3);
    }
#undef FRAG_HI
#undef FRAG_LO
#undef LOADW
#undef LOADA_HI
#undef LOADA_LO

    // ---- epilogue: per-wave LDS transpose -> fp16 half4 stores.
    // __syncthreads() fences between scatter and gather (r17-verified).
    float* wbase = eplds + wid * 1088;
    const float4 bv4 = *reinterpret_cast<const float4*>(
        &bias[col0 + wn * 64 + l15 * 4]);

#pragma unroll
    for (int mf = 0; mf < 8; ++mf) {
#pragma unroll
        for (int nf = 0; nf < 4; ++nf)
#pragma unroll
            for (int j = 0; j < 4; ++j)
                wbase[(kq * 4 + j) * 68 + nf * 16 + l15] = acc[mf][nf][j];
        __syncthreads();   // writes visible before cross-lane reads
#pragma unroll
        for (int i = 0; i < 4; ++i) {
            const int r16 = i * 4 + kq;
            float4 v = *reinterpret_cast<float4*>(wbase + r16 * 68 + l15 * 4);
            half4 h;
            h[0] = (_Float16)(v.x + bv4.x);   // RNE
            h[1] = (_Float16)(v.y + bv4.y);
            h[2] = (_Float16)(v.z + bv4.z);
            h[3] = (_Float16)(v.w + bv4.w);
            const int r = row0 + wm * 128 + mf * 16 + r16;
            *reinterpret_cast<half4*>(
                &C[(size_t)r * 1536 + col0 + wn * 64 + l15 * 4]) = h;
        }
        __syncthreads();   // reads done before next mf's scatter overwrites
    }
}

// ---------------------------------------------------------------------------
// k2: scrambled elementwise softmax; qkv FP16 (r18-verified)
// ---------------------------------------------------------------------------
__global__ __launch_bounds__(256) void attn_scramble(
    const _Float16* __restrict__ qkv, float* __restrict__ out)
{
    __shared__ float Ks[64][68];    // [hwlo][d'], rows 272B (16B-aligned)
    const int bid = blockIdx.x;
    const int hw6 = bid & 63;
    const int n   = (bid >> 6) & 7;
    const int b   = bid >> 9;
    const int kn  = (n + 7) & 7;
    const int t   = threadIdx.x;
    {
        const int lx = t & 7;       // 8 lanes x half8 cover one d'-row (64)
        const int rp = t >> 3;      // 32 d'-rows per pass
#pragma unroll
        for (int p = 0; p < 2; ++p) {
            const int dp = p * 32 + rp;
            const half8 kv = *reinterpret_cast<const half8*>(
                &qkv[(size_t)(b * 4096 + dp * 64 + hw6) * 1536 + 512 +
                     kn * 64 + lx * 8]);
#pragma unroll
            for (int e = 0; e < 8; ++e)
                Ks[lx * 8 + e][dp] = (float)kv[e];
        }
    }
    __syncthreads();
    const int row = t >> 2;
    const int tl  = t & 3;
    const size_t rbase = (size_t)(b * 4096 + hw6 * 64 + row) * 1536;
    float s[16];
    {
        const _Float16* qp = qkv + rbase + n * 64 + tl * 16;
        const half8 q0 = *reinterpret_cast<const half8*>(qp);
        const half8 q1 = *reinterpret_cast<const half8*>(qp + 8);
        float q[16], kk[16];
#pragma unroll
        for (int e = 0; e < 8; ++e) {
            q[e] = (float)q0[e];
            q[8 + e] = (float)q1[e];
        }
#pragma unroll
        for (int u = 0; u < 4; ++u)
            *reinterpret_cast<float4*>(&kk[u * 4]) =
                *reinterpret_cast<const float4*>(&Ks[row][tl * 16 + u * 4]);
        float m = -1e30f;
#pragma unroll
        for (int u = 0; u < 16; ++u) {
            s[u] = 0.125f * q[u] * kk[u];
            m = fmaxf(m, s[u]);
        }
        m = fmaxf(m, __shfl_xor(m, 1));
        m = fmaxf(m, __shfl_xor(m, 2));
        float sum = 0.f;
#pragma unroll
        for (int u = 0; u < 16; ++u) {
            s[u] = __expf(s[u] - m);
            sum += s[u];
        }
        sum += __shfl_xor(sum, 1);
        sum += __shfl_xor(sum, 2);
        const float inv = 1.0f / sum;
#pragma unroll
        for (int u = 0; u < 16; ++u) s[u] *= inv;
    }
    const _Float16* vp = qkv + rbase + 1024 + kn * 64 + tl * 16;
    const half8 v0 = *reinterpret_cast<const half8*>(vp);
    const half8 v1 = *reinterpret_cast<const half8*>(vp + 8);
    const int vb = b >> 3, fr = b & 7;
    float* op = out +
        ((size_t)(((vb * 8 + (hw6 >> 3)) * 64 + ((hw6 & 7) * 8 + (row >> 3))) * 64 +
                  ((row & 7) * 8 + n)) * 512) + fr * 64 + tl * 16;
    float4 o0, o1, o2, o3;
    o0.x = s[0]  * (float)v0[0]; o0.y = s[1]  * (float)v0[1];
    o0.z = s[2]  * (float)v0[2]; o0.w = s[3]  * (float)v0[3];
    o1.x = s[4]  * (float)v0[4]; o1.y = s[5]  * (float)v0[5];
    o1.z = s[6]  * (float)v0[6]; o1.w = s[7]  * (float)v0[7];
    o2.x = s[8]  * (float)v1[0]; o2.y = s[9]  * (float)v1[1];
    o2.z = s[10] * (float)v1[2]; o2.w = s[11] * (float)v1[3];
    o3.x = s[12] * (float)v1[4]; o3.y = s[13] * (float)v1[5];
    o3.z = s[14] * (float)v1[6]; o3.w = s[15] * (float)v1[7];
    *reinterpret_cast<float4*>(op)      = o0;
    *reinterpret_cast<float4*>(op + 4)  = o1;
    *reinterpret_cast<float4*>(op + 8)  = o2;
    *reinterpret_cast<float4*>(op + 12) = o3;
}

// ---------------------------------------------------------------------------
extern "C" void kernel_launch(void* const* d_in, const int* in_sizes, int n_in,
                              void* d_out, int out_size, void* d_ws, size_t ws_size,
                              hipStream_t stream) {
    const float* hs = (const float*)d_in[0];  // [65536,512]
    const float* w  = (const float*)d_in[1];  // [1536,512]
    const float* bq = (const float*)d_in[2];  // [1536]
    float* out = (float*)d_out;
    _Float16* qkv = (_Float16*)d_ws;          // 201,326,592 B (fits)

    // d_out as scratch: Af (67,108,864 B) | Wf (1,572,864 B)
    _Float16* Af = (_Float16*)d_out;
    _Float16* Wf = Af + 33554432;             // 65536*512

    cvt_a_frag<<<16384, 256, 0, stream>>>(hs, Af);
    cvt_w_frag<<<384, 256, 0, stream>>>(w, Wf);
    gemm_nolds4<<<3072, 256, 0, stream>>>(Af, Wf, bq, qkv);
    attn_scramble<<<8192, 256, 0, stream>>>(qkv, out);
}